// Round 25
// baseline (106.596 us; speedup 1.0000x reference)
//
#include <hip/hip_runtime.h>
#include <hip/hip_bf16.h>
#include <stdint.h>

// B=4, C=256, N=4096, dk=32
typedef float f32x16 __attribute__((ext_vector_type(16)));
typedef short bf16x8 __attribute__((ext_vector_type(8)));

#define L2E 1.4426950408889634f
#define ROWPAT(r, hi) (((r) & 3) + 8 * ((r) >> 2) + 4 * (hi))

// ws layout (bytes): Wcb 160KB | qbuf 1MB | kbuf 1MB | vbuf 8MB
#define WCATB_OFF 0u
#define QBUF_OFF  163840u
#define KBUF_OFF  1212416u
#define VBUF_OFF  2260992u

static __device__ __forceinline__ ushort f2bf(float f) {
    union { float f; uint32_t u; } v; v.f = f;
    uint32_t u = v.u;
    return (ushort)((u + 0x7fffu + ((u >> 16) & 1u)) >> 16);
}

static __device__ __forceinline__ uint32_t cvtpk(float lo, float hi) {
    uint32_t r;
    asm volatile("v_cvt_pk_bf16_f32 %0, %1, %2" : "=v"(r) : "v"(lo), "v"(hi));
    return r;
}
// p[j] at D-pattern m' = (j&3)+8*(j>>2)+4*hi; -> B-frag words for 16 keys.
static __device__ __forceinline__ bf16x8 packP(float p0, float p1, float p2, float p3,
                                               float p4, float p5, float p6, float p7) {
    uint32_t a0 = cvtpk(p0, p1), a1 = cvtpk(p2, p3);
    uint32_t b0 = cvtpk(p4, p5), b1 = cvtpk(p6, p7);
    auto s0 = __builtin_amdgcn_permlane32_swap(a0, b0, false, false);
    auto s1 = __builtin_amdgcn_permlane32_swap(a1, b1, false, false);
    union { uint32_t u[4]; bf16x8 v; } pk;
    pk.u[0] = s0[0];
    pk.u[1] = s1[0];
    pk.u[2] = s0[1];
    pk.u[3] = s1[1];
    return pk.v;
}

// ---------------- prep: Wcat_bf16 [320][256] ----------------
__global__ void prep_kernel(const float* __restrict__ Wq, const float* __restrict__ Wk,
                            const float* __restrict__ Wv, ushort* __restrict__ Wcb) {
    int row = blockIdx.x, c = threadIdx.x;
    float v;
    if (row < 32)      v = Wq[row * 256 + c];
    else if (row < 64) v = Wk[(row - 32) * 256 + c];
    else               v = Wv[(row - 64) * 256 + c];
    Wcb[row * 256 + c] = f2bf(v);
}

// ---------------- fused proj v2 (R24, validated): 8 waves -------------------
__global__ __launch_bounds__(512)
void fproj_kernel(const float* __restrict__ x, const ushort* __restrict__ Wcb,
                  const float* __restrict__ bq, const float* __restrict__ bk,
                  const float* __restrict__ bv,
                  ushort* __restrict__ qbuf, ushort* __restrict__ kbuf,
                  ushort* __restrict__ vbuf) {
    __shared__ ushort xt[32 * 264];   // [n][c] bf16, stride 264
    const int tid = threadIdx.x;
    const int b = blockIdx.x >> 7;
    const int n0 = (blockIdx.x & 127) << 5;

    const float* xb = x + (((size_t)b) << 20) + n0;   // b*256*4096
    #pragma unroll
    for (int i = 0; i < 4; ++i) {
        int task = tid + (i << 9);
        int c = task >> 3, seg = task & 7;
        float4 v = *(const float4*)(xb + (size_t)c * 4096 + seg * 4);
        xt[(seg * 4 + 0) * 264 + c] = f2bf(v.x);
        xt[(seg * 4 + 1) * 264 + c] = f2bf(v.y);
        xt[(seg * 4 + 2) * 264 + c] = f2bf(v.z);
        xt[(seg * 4 + 3) * 264 + c] = f2bf(v.w);
    }
    __syncthreads();

    const int w = tid >> 6, l = tid & 63;
    const int l31 = l & 31, hi = l >> 5;

    for (int cc = w; cc < 10; cc += 8) {
        const int wbase = (cc < 2) ? cc * 32 : (cc - 2) * 32 + 64;
        const ushort* wrow = Wcb + (size_t)(wbase + l31) * 256;
        f32x16 acc = (f32x16)0.0f;
        if (cc < 2) {
            #pragma unroll
            for (int kk = 0; kk < 16; ++kk) {
                bf16x8 xf = *(const bf16x8*)&xt[l31 * 264 + kk * 16 + hi * 8];
                bf16x8 wf = *(const bf16x8*)&wrow[kk * 16 + hi * 8];
                acc = __builtin_amdgcn_mfma_f32_32x32x16_bf16(xf, wf, acc, 0, 0, 0);
            }
            const float bias = (cc == 0) ? bq[l31] : bk[l31];
            const float scale = (cc == 0) ? L2E : 1.0f;
            ushort* dst = (cc == 0) ? qbuf : kbuf;
            #pragma unroll
            for (int r = 0; r < 16; ++r) {
                int n = n0 + ROWPAT(r, hi);
                dst[((size_t)((b << 12) + n)) * 32 + l31] = f2bf((acc[r] + bias) * scale);
            }
        } else {
            #pragma unroll
            for (int kk = 0; kk < 16; ++kk) {
                bf16x8 wf = *(const bf16x8*)&wrow[kk * 16 + hi * 8];
                bf16x8 xf = *(const bf16x8*)&xt[l31 * 264 + kk * 16 + hi * 8];
                acc = __builtin_amdgcn_mfma_f32_32x32x16_bf16(wf, xf, acc, 0, 0, 0);
            }
            #pragma unroll
            for (int r = 0; r < 16; ++r) {
                int c = (wbase - 64) + ROWPAT(r, hi);
                vbuf[((size_t)(b * 256 + c)) * 4096 + n0 + l31] = f2bf(acc[r] + bv[c]);
            }
        }
    }
}

// ---------------- attention v17: R20-final + per-block phase rotation -------
// Single-variable A/B vs R24: each block processes the 64 key-tiles in a
// rotated order tile=(k+roff)&63, roff=(bid*37)&63. Commutative no-max
// softmax => identical math (fp32 sum reorder only). De-phases the two
// co-resident blocks' load/LDS/barrier bursts (they previously ran
// bit-identical schedules in lockstep, contending in bursts).
#define KSTR 36
#define VSTR 66
__global__ __launch_bounds__(256, 2)
void attn_kernel(const ushort* __restrict__ qbuf, const ushort* __restrict__ kbuf,
                 const ushort* __restrict__ vbuf, const float* __restrict__ x,
                 const float* __restrict__ gammap, float* __restrict__ out) {
    __shared__ ushort klds[2][64 * KSTR];   // 9 KB
    __shared__ ushort vlds[2][256 * VSTR];  // 66 KB (reused as 32KB f32 scratch)
    __shared__ float  dlds[2][32];

    const int tid = threadIdx.x;
    const int bid = blockIdx.x;
    const int work = (bid & 7) * 64 + (bid >> 3);   // XCD-cluster
    const int b = work >> 7;
    const int qbase = (work & 127) << 5;
    const int roff = (bid * 37) & 63;               // per-block tile phase
    const int w = tid >> 6, l = tid & 63;
    const int l31 = l & 31, hi = l >> 5;
    const int kh = w >> 1, cp = w & 1;

    const ushort* kb = kbuf + ((size_t)b << 12) * 32;
    const ushort* vb = vbuf + ((size_t)b << 8) * 4096;

    const ushort* qrow = qbuf + ((size_t)((b << 12) + qbase + l31)) * 32;
    const bf16x8 qf0 = *(const bf16x8*)&qrow[hi * 8];
    const bf16x8 qf1 = *(const bf16x8*)&qrow[16 + hi * 8];

    f32x16 acc[4];
    #pragma unroll
    for (int ch = 0; ch < 4; ++ch) acc[ch] = (f32x16)0.0f;
    float dsum = 0.f;

    const int vc = tid >> 3, vs = tid & 7;
    const int krow = tid >> 2, kseg = tid & 3;
    const ushort* vsrc = vb + (size_t)vc * 4096 + vs * 8;
    const ushort* ksrc = kb + (size_t)krow * 32 + kseg * 8;
    uint4 vreg[8], kreg;

    const int krow_a = (kh * 32 + l31) * KSTR;

    // pipeline states (named, static)
    bf16x8 pA0, pA1, pB0, pB1;
    bf16x8 vA0, vA1, vA2, vA3, vA4, vA5, vA6, vA7;
    bf16x8 vB0, vB1, vB2, vB3, vB4, vB5, vB6, vB7;

#define QK_EXP_LOAD(CUR, PC0, PC1, VC0, VC1, VC2, VC3, VC4, VC5, VC6, VC7)     \
    {                                                                          \
        bf16x8 kf0 = *(const bf16x8*)&klds[CUR][krow_a + hi * 8];              \
        bf16x8 kf1 = *(const bf16x8*)&klds[CUR][krow_a + 16 + hi * 8];         \
        f32x16 sT = __builtin_amdgcn_mfma_f32_32x32x16_bf16(kf0, qf0,          \
                                                    (f32x16)0.0f, 0, 0, 0);    \
        sT = __builtin_amdgcn_mfma_f32_32x32x16_bf16(kf1, qf1, sT, 0, 0, 0);   \
        float p[16];                                                           \
        _Pragma("unroll")                                                      \
        for (int r = 0; r < 16; ++r) {                                         \
            p[r] = __builtin_amdgcn_exp2f(sT[r]);                              \
            dsum += p[r];                                                      \
        }                                                                      \
        PC0 = packP(p[0], p[1], p[2], p[3], p[4], p[5], p[6], p[7]);           \
        PC1 = packP(p[8], p[9], p[10], p[11], p[12], p[13], p[14], p[15]);     \
        const int cr0 = (cp * 128 + 0 * 32 + l31) * VSTR + kh * 32;            \
        const int cr1 = (cp * 128 + 1 * 32 + l31) * VSTR + kh * 32;            \
        const int cr2 = (cp * 128 + 2 * 32 + l31) * VSTR + kh * 32;            \
        const int cr3 = (cp * 128 + 3 * 32 + l31) * VSTR + kh * 32;            \
        VC0 = *(const bf16x8*)&vlds[CUR][cr0 + hi * 8];                        \
        VC1 = *(const bf16x8*)&vlds[CUR][cr0 + 16 + hi * 8];                   \
        VC2 = *(const bf16x8*)&vlds[CUR][cr1 + hi * 8];                        \
        VC3 = *(const bf16x8*)&vlds[CUR][cr1 + 16 + hi * 8];                   \
        VC4 = *(const bf16x8*)&vlds[CUR][cr2 + hi * 8];                        \
        VC5 = *(const bf16x8*)&vlds[CUR][cr2 + 16 + hi * 8];                   \
        VC6 = *(const bf16x8*)&vlds[CUR][cr3 + hi * 8];                        \
        VC7 = *(const bf16x8*)&vlds[CUR][cr3 + 16 + hi * 8];                   \
    }

#define PV_OTHER(PO0, PO1, VO0, VO1, VO2, VO3, VO4, VO5, VO6, VO7)             \
    {                                                                          \
        __builtin_amdgcn_s_setprio(1);                                         \
        acc[0] = __builtin_amdgcn_mfma_f32_32x32x16_bf16(VO0, PO0, acc[0], 0, 0, 0); \
        acc[0] = __builtin_amdgcn_mfma_f32_32x32x16_bf16(VO1, PO1, acc[0], 0, 0, 0); \
        acc[1] = __builtin_amdgcn_mfma_f32_32x32x16_bf16(VO2, PO0, acc[1], 0, 0, 0); \
        acc[1] = __builtin_amdgcn_mfma_f32_32x32x16_bf16(VO3, PO1, acc[1], 0, 0, 0); \
        acc[2] = __builtin_amdgcn_mfma_f32_32x32x16_bf16(VO4, PO0, acc[2], 0, 0, 0); \
        acc[2] = __builtin_amdgcn_mfma_f32_32x32x16_bf16(VO5, PO1, acc[2], 0, 0, 0); \
        acc[3] = __builtin_amdgcn_mfma_f32_32x32x16_bf16(VO6, PO0, acc[3], 0, 0, 0); \
        acc[3] = __builtin_amdgcn_mfma_f32_32x32x16_bf16(VO7, PO1, acc[3], 0, 0, 0); \
        __builtin_amdgcn_s_setprio(0);                                         \
    }

#define PREFETCH(KNEXT)                                                        \
    {                                                                          \
        const size_t m0 = (size_t)(((KNEXT) + roff) & 63) << 6;                \
        _Pragma("unroll")                                                      \
        for (int i = 0; i < 8; ++i)                                            \
            vreg[i] = *(const uint4*)(vsrc + (size_t)i * 32 * 4096 + m0);      \
        kreg = *(const uint4*)(ksrc + (m0 << 5));                              \
    }

#define STAGE_WRITE(DSTBUF)                                                    \
    {                                                                          \
        _Pragma("unroll")                                                      \
        for (int i = 0; i < 8; ++i)                                            \
            *(uint4*)&vlds[DSTBUF][(vc + 32 * i) * VSTR + vs * 8] = vreg[i];   \
        *(uint4*)&klds[DSTBUF][krow * KSTR + kseg * 8] = kreg;                 \
    }

    // prologue: stage (rotated) tile 0 -> buf0
    PREFETCH(0);
    STAGE_WRITE(0);
    __syncthreads();
    // compute tile 0 into A; stage tile 1 -> buf1
    PREFETCH(1);
    QK_EXP_LOAD(0, pA0, pA1, vA0, vA1, vA2, vA3, vA4, vA5, vA6, vA7);
    STAGE_WRITE(1);
    __syncthreads();

    // main: pairs (k, k+1) for k = 1,3,...,61  (logical tiles 1..62)
    for (int k = 1; k < 62; k += 2) {
        // tile k (odd -> buf1): compute into B, PV(A), stage k+1 -> buf0
        PREFETCH(k + 1);
        QK_EXP_LOAD(1, pB0, pB1, vB0, vB1, vB2, vB3, vB4, vB5, vB6, vB7);
        PV_OTHER(pA0, pA1, vA0, vA1, vA2, vA3, vA4, vA5, vA6, vA7);
        STAGE_WRITE(0);
        __syncthreads();
        // tile k+1 (even -> buf0): compute into A, PV(B), stage k+2 -> buf1
        PREFETCH(k + 2);
        QK_EXP_LOAD(0, pA0, pA1, vA0, vA1, vA2, vA3, vA4, vA5, vA6, vA7);
        PV_OTHER(pB0, pB1, vB0, vB1, vB2, vB3, vB4, vB5, vB6, vB7);
        STAGE_WRITE(1);
        __syncthreads();
    }
    // logical tile 63 (buf1): compute into B, PV(A); no more staging
    QK_EXP_LOAD(1, pB0, pB1, vB0, vB1, vB2, vB3, vB4, vB5, vB6, vB7);
    PV_OTHER(pA0, pA1, vA0, vA1, vA2, vA3, vA4, vA5, vA6, vA7);
    // drain PV(B)
    PV_OTHER(pB0, pB1, vB0, vB1, vB2, vB3, vB4, vB5, vB6, vB7);

#undef QK_EXP_LOAD
#undef PV_OTHER
#undef PREFETCH
#undef STAGE_WRITE

    // ---- cross-kh combine + epilogue ----
    const float gam = gammap[0];
    float dall = dsum + __shfl_xor(dsum, 32);
    float* scr = (float*)&vlds[0][0];   // 32 KB scratch
    __syncthreads();   // all PV reads of vlds done; safe to reuse
    if (kh == 1) {
        #pragma unroll
        for (int ch = 0; ch < 4; ++ch)
            #pragma unroll
            for (int r = 0; r < 16; ++r)
                scr[(((cp * 4 + ch) * 16 + r) << 6) + l] = acc[ch][r];
    }
    if (cp == 0 && l < 32) dlds[kh][l31] = dall;
    __syncthreads();
    if (kh == 0) {
        const float denom = dlds[0][l31] + dlds[1][l31];
        const float ginv = gam / denom;
        const float* xb2 = x + (((size_t)b) << 8) * 4096;
        float* ob = out + (((size_t)b) << 8) * 4096;
        const int q = qbase + l31;
        #pragma unroll
        for (int ch = 0; ch < 4; ++ch) {
            #pragma unroll
            for (int r = 0; r < 16; ++r) {
                int c = cp * 128 + ch * 32 + ROWPAT(r, hi);
                float o = acc[ch][r] + scr[(((cp * 4 + ch) * 16 + r) << 6) + l];
                size_t idx = (size_t)c * 4096 + q;
                ob[idx] = o * ginv + xb2[idx];
            }
        }
    }
}

extern "C" void kernel_launch(void* const* d_in, const int* in_sizes, int n_in,
                              void* d_out, int out_size, void* d_ws, size_t ws_size,
                              hipStream_t stream) {
    (void)in_sizes; (void)n_in; (void)out_size; (void)ws_size;
    const float* x     = (const float*)d_in[0];
    const float* Wq    = (const float*)d_in[1];
    const float* bq    = (const float*)d_in[2];
    const float* Wk    = (const float*)d_in[3];
    const float* bk    = (const float*)d_in[4];
    const float* Wv    = (const float*)d_in[5];
    const float* bv    = (const float*)d_in[6];
    const float* gamma = (const float*)d_in[7];
    float* out = (float*)d_out;

    char* ws = (char*)d_ws;
    ushort* Wcb  = (ushort*)(ws + WCATB_OFF);
    ushort* qbuf = (ushort*)(ws + QBUF_OFF);
    ushort* kbuf = (ushort*)(ws + KBUF_OFF);
    ushort* vbuf = (ushort*)(ws + VBUF_OFF);

    prep_kernel<<<320, 256, 0, stream>>>(Wq, Wk, Wv, Wcb);
    fproj_kernel<<<512, 512, 0, stream>>>(x, Wcb, bq, bk, bv, qbuf, kbuf, vbuf);
    attn_kernel<<<512, 256, 0, stream>>>(qbuf, kbuf, vbuf, x, gamma, out);
}

// Round 26
// 104.276 us; speedup vs baseline: 1.0222x; 1.0222x over previous
//
#include <hip/hip_runtime.h>
#include <hip/hip_bf16.h>
#include <stdint.h>

// B=4, C=256, N=4096, dk=32
typedef float f32x16 __attribute__((ext_vector_type(16)));
typedef short bf16x8 __attribute__((ext_vector_type(8)));

#define L2E 1.4426950408889634f
#define ROWPAT(r, hi) (((r) & 3) + 8 * ((r) >> 2) + 4 * (hi))

// ws layout (bytes): Wcb 160KB | qbuf 1MB | kbuf 1MB | vbuf 8MB
#define WCATB_OFF 0u
#define QBUF_OFF  163840u
#define KBUF_OFF  1212416u
#define VBUF_OFF  2260992u

static __device__ __forceinline__ ushort f2bf(float f) {
    union { float f; uint32_t u; } v; v.f = f;
    uint32_t u = v.u;
    return (ushort)((u + 0x7fffu + ((u >> 16) & 1u)) >> 16);
}

static __device__ __forceinline__ uint32_t cvtpk(float lo, float hi) {
    uint32_t r;
    asm volatile("v_cvt_pk_bf16_f32 %0, %1, %2" : "=v"(r) : "v"(lo), "v"(hi));
    return r;
}
// p[j] at D-pattern m' = (j&3)+8*(j>>2)+4*hi; -> B-frag words for 16 keys.
static __device__ __forceinline__ bf16x8 packP(float p0, float p1, float p2, float p3,
                                               float p4, float p5, float p6, float p7) {
    uint32_t a0 = cvtpk(p0, p1), a1 = cvtpk(p2, p3);
    uint32_t b0 = cvtpk(p4, p5), b1 = cvtpk(p6, p7);
    auto s0 = __builtin_amdgcn_permlane32_swap(a0, b0, false, false);
    auto s1 = __builtin_amdgcn_permlane32_swap(a1, b1, false, false);
    union { uint32_t u[4]; bf16x8 v; } pk;
    pk.u[0] = s0[0];
    pk.u[1] = s1[0];
    pk.u[2] = s0[1];
    pk.u[3] = s1[1];
    return pk.v;
}

// ---------------- prep: Wcat_bf16 [320][256] ----------------
__global__ void prep_kernel(const float* __restrict__ Wq, const float* __restrict__ Wk,
                            const float* __restrict__ Wv, ushort* __restrict__ Wcb) {
    int row = blockIdx.x, c = threadIdx.x;
    float v;
    if (row < 32)      v = Wq[row * 256 + c];
    else if (row < 64) v = Wk[(row - 32) * 256 + c];
    else               v = Wv[(row - 64) * 256 + c];
    Wcb[row * 256 + c] = f2bf(v);
}

// ---------------- fused proj v2 (R24, validated): 8 waves -------------------
// grid 512 = 4b x 128 n-tiles(32). Block 512 thr = 8 waves; 10 MFMA chains
// (Q, K, V0..V7) distributed cc = w, w+8 (makespan 2 chains). Q pre-scaled
// by log2(e).
__global__ __launch_bounds__(512)
void fproj_kernel(const float* __restrict__ x, const ushort* __restrict__ Wcb,
                  const float* __restrict__ bq, const float* __restrict__ bk,
                  const float* __restrict__ bv,
                  ushort* __restrict__ qbuf, ushort* __restrict__ kbuf,
                  ushort* __restrict__ vbuf) {
    __shared__ ushort xt[32 * 264];   // [n][c] bf16, stride 264
    const int tid = threadIdx.x;
    const int b = blockIdx.x >> 7;
    const int n0 = (blockIdx.x & 127) << 5;

    const float* xb = x + (((size_t)b) << 20) + n0;   // b*256*4096
    #pragma unroll
    for (int i = 0; i < 4; ++i) {
        int task = tid + (i << 9);
        int c = task >> 3, seg = task & 7;
        float4 v = *(const float4*)(xb + (size_t)c * 4096 + seg * 4);
        xt[(seg * 4 + 0) * 264 + c] = f2bf(v.x);
        xt[(seg * 4 + 1) * 264 + c] = f2bf(v.y);
        xt[(seg * 4 + 2) * 264 + c] = f2bf(v.z);
        xt[(seg * 4 + 3) * 264 + c] = f2bf(v.w);
    }
    __syncthreads();

    const int w = tid >> 6, l = tid & 63;
    const int l31 = l & 31, hi = l >> 5;

    for (int cc = w; cc < 10; cc += 8) {
        const int wbase = (cc < 2) ? cc * 32 : (cc - 2) * 32 + 64;
        const ushort* wrow = Wcb + (size_t)(wbase + l31) * 256;
        f32x16 acc = (f32x16)0.0f;
        if (cc < 2) {
            // Q/K: A = xt rows (n), B = W rows (m); D[n][m], col=l31=m
            #pragma unroll
            for (int kk = 0; kk < 16; ++kk) {
                bf16x8 xf = *(const bf16x8*)&xt[l31 * 264 + kk * 16 + hi * 8];
                bf16x8 wf = *(const bf16x8*)&wrow[kk * 16 + hi * 8];
                acc = __builtin_amdgcn_mfma_f32_32x32x16_bf16(xf, wf, acc, 0, 0, 0);
            }
            const float bias = (cc == 0) ? bq[l31] : bk[l31];
            const float scale = (cc == 0) ? L2E : 1.0f;
            ushort* dst = (cc == 0) ? qbuf : kbuf;
            #pragma unroll
            for (int r = 0; r < 16; ++r) {
                int n = n0 + ROWPAT(r, hi);
                dst[((size_t)((b << 12) + n)) * 32 + l31] = f2bf((acc[r] + bias) * scale);
            }
        } else {
            // V: A = W rows (c), B = xt rows (n); D[c][n], col=l31=n
            #pragma unroll
            for (int kk = 0; kk < 16; ++kk) {
                bf16x8 wf = *(const bf16x8*)&wrow[kk * 16 + hi * 8];
                bf16x8 xf = *(const bf16x8*)&xt[l31 * 264 + kk * 16 + hi * 8];
                acc = __builtin_amdgcn_mfma_f32_32x32x16_bf16(wf, xf, acc, 0, 0, 0);
            }
            #pragma unroll
            for (int r = 0; r < 16; ++r) {
                int c = (wbase - 64) + ROWPAT(r, hi);
                vbuf[((size_t)(b * 256 + c)) * 4096 + n0 + l31] = f2bf(acc[r] + bv[c]);
            }
        }
    }
}

// ---------------- attention (final, best measured: 92.3us) ------------------
// grid 512 (XCD-clustered) = 4b x 128 qtiles(32q); block 256 = 4 waves.
// wave w: kh=w>>1 (32 keys), cp=w&1 (128 channels). T15 named-state pipeline
// (PV(k-1) overlaps QK(k)/exp(k)); bare v_exp via __builtin_amdgcn_exp2f;
// single staging set, sequential tile order (phase rotation regresses, R25).
// 2 blocks/CU. Measured: VGPR 120, MfmaUtil ~19%, VALUBusy ~23.5%.
#define KSTR 36
#define VSTR 66
__global__ __launch_bounds__(256, 2)
void attn_kernel(const ushort* __restrict__ qbuf, const ushort* __restrict__ kbuf,
                 const ushort* __restrict__ vbuf, const float* __restrict__ x,
                 const float* __restrict__ gammap, float* __restrict__ out) {
    __shared__ ushort klds[2][64 * KSTR];   // 9 KB
    __shared__ ushort vlds[2][256 * VSTR];  // 66 KB (reused as 32KB f32 scratch)
    __shared__ float  dlds[2][32];

    const int tid = threadIdx.x;
    const int bid = blockIdx.x;
    const int work = (bid & 7) * 64 + (bid >> 3);   // XCD-cluster
    const int b = work >> 7;
    const int qbase = (work & 127) << 5;
    const int w = tid >> 6, l = tid & 63;
    const int l31 = l & 31, hi = l >> 5;
    const int kh = w >> 1, cp = w & 1;

    const ushort* kb = kbuf + ((size_t)b << 12) * 32;
    const ushort* vb = vbuf + ((size_t)b << 8) * 4096;

    const ushort* qrow = qbuf + ((size_t)((b << 12) + qbase + l31)) * 32;
    const bf16x8 qf0 = *(const bf16x8*)&qrow[hi * 8];
    const bf16x8 qf1 = *(const bf16x8*)&qrow[16 + hi * 8];

    f32x16 acc[4];
    #pragma unroll
    for (int ch = 0; ch < 4; ++ch) acc[ch] = (f32x16)0.0f;
    float dsum = 0.f;

    const int vc = tid >> 3, vs = tid & 7;
    const int krow = tid >> 2, kseg = tid & 3;
    const ushort* vsrc = vb + (size_t)vc * 4096 + vs * 8;
    const ushort* ksrc = kb + (size_t)krow * 32 + kseg * 8;
    uint4 vreg[8], kreg;

    const int krow_a = (kh * 32 + l31) * KSTR;

    // pipeline states (named, static)
    bf16x8 pA0, pA1, pB0, pB1;
    bf16x8 vA0, vA1, vA2, vA3, vA4, vA5, vA6, vA7;
    bf16x8 vB0, vB1, vB2, vB3, vB4, vB5, vB6, vB7;

#define QK_EXP_LOAD(CUR, PC0, PC1, VC0, VC1, VC2, VC3, VC4, VC5, VC6, VC7)     \
    {                                                                          \
        bf16x8 kf0 = *(const bf16x8*)&klds[CUR][krow_a + hi * 8];              \
        bf16x8 kf1 = *(const bf16x8*)&klds[CUR][krow_a + 16 + hi * 8];         \
        f32x16 sT = __builtin_amdgcn_mfma_f32_32x32x16_bf16(kf0, qf0,          \
                                                    (f32x16)0.0f, 0, 0, 0);    \
        sT = __builtin_amdgcn_mfma_f32_32x32x16_bf16(kf1, qf1, sT, 0, 0, 0);   \
        float p[16];                                                           \
        _Pragma("unroll")                                                      \
        for (int r = 0; r < 16; ++r) {                                         \
            p[r] = __builtin_amdgcn_exp2f(sT[r]);                              \
            dsum += p[r];                                                      \
        }                                                                      \
        PC0 = packP(p[0], p[1], p[2], p[3], p[4], p[5], p[6], p[7]);           \
        PC1 = packP(p[8], p[9], p[10], p[11], p[12], p[13], p[14], p[15]);     \
        const int cr0 = (cp * 128 + 0 * 32 + l31) * VSTR + kh * 32;            \
        const int cr1 = (cp * 128 + 1 * 32 + l31) * VSTR + kh * 32;            \
        const int cr2 = (cp * 128 + 2 * 32 + l31) * VSTR + kh * 32;            \
        const int cr3 = (cp * 128 + 3 * 32 + l31) * VSTR + kh * 32;            \
        VC0 = *(const bf16x8*)&vlds[CUR][cr0 + hi * 8];                        \
        VC1 = *(const bf16x8*)&vlds[CUR][cr0 + 16 + hi * 8];                   \
        VC2 = *(const bf16x8*)&vlds[CUR][cr1 + hi * 8];                        \
        VC3 = *(const bf16x8*)&vlds[CUR][cr1 + 16 + hi * 8];                   \
        VC4 = *(const bf16x8*)&vlds[CUR][cr2 + hi * 8];                        \
        VC5 = *(const bf16x8*)&vlds[CUR][cr2 + 16 + hi * 8];                   \
        VC6 = *(const bf16x8*)&vlds[CUR][cr3 + hi * 8];                        \
        VC7 = *(const bf16x8*)&vlds[CUR][cr3 + 16 + hi * 8];                   \
    }

#define PV_OTHER(PO0, PO1, VO0, VO1, VO2, VO3, VO4, VO5, VO6, VO7)             \
    {                                                                          \
        __builtin_amdgcn_s_setprio(1);                                         \
        acc[0] = __builtin_amdgcn_mfma_f32_32x32x16_bf16(VO0, PO0, acc[0], 0, 0, 0); \
        acc[0] = __builtin_amdgcn_mfma_f32_32x32x16_bf16(VO1, PO1, acc[0], 0, 0, 0); \
        acc[1] = __builtin_amdgcn_mfma_f32_32x32x16_bf16(VO2, PO0, acc[1], 0, 0, 0); \
        acc[1] = __builtin_amdgcn_mfma_f32_32x32x16_bf16(VO3, PO1, acc[1], 0, 0, 0); \
        acc[2] = __builtin_amdgcn_mfma_f32_32x32x16_bf16(VO4, PO0, acc[2], 0, 0, 0); \
        acc[2] = __builtin_amdgcn_mfma_f32_32x32x16_bf16(VO5, PO1, acc[2], 0, 0, 0); \
        acc[3] = __builtin_amdgcn_mfma_f32_32x32x16_bf16(VO6, PO0, acc[3], 0, 0, 0); \
        acc[3] = __builtin_amdgcn_mfma_f32_32x32x16_bf16(VO7, PO1, acc[3], 0, 0, 0); \
        __builtin_amdgcn_s_setprio(0);                                         \
    }

#define PREFETCH(KNEXT)                                                        \
    {                                                                          \
        const size_t m0 = (size_t)(KNEXT) << 6;                                \
        _Pragma("unroll")                                                      \
        for (int i = 0; i < 8; ++i)                                            \
            vreg[i] = *(const uint4*)(vsrc + (size_t)i * 32 * 4096 + m0);      \
        kreg = *(const uint4*)(ksrc + (m0 << 5));                              \
    }

#define STAGE_WRITE(DSTBUF)                                                    \
    {                                                                          \
        _Pragma("unroll")                                                      \
        for (int i = 0; i < 8; ++i)                                            \
            *(uint4*)&vlds[DSTBUF][(vc + 32 * i) * VSTR + vs * 8] = vreg[i];   \
        *(uint4*)&klds[DSTBUF][krow * KSTR + kseg * 8] = kreg;                 \
    }

    // prologue: stage tile 0 -> buf0
    PREFETCH(0);
    STAGE_WRITE(0);
    __syncthreads();
    // compute tile 0 into A; stage tile 1 -> buf1
    PREFETCH(1);
    QK_EXP_LOAD(0, pA0, pA1, vA0, vA1, vA2, vA3, vA4, vA5, vA6, vA7);
    STAGE_WRITE(1);
    __syncthreads();

    // main: pairs (k, k+1) for k = 1,3,...,61  (tiles 1..62)
    for (int k = 1; k < 62; k += 2) {
        // tile k (odd -> buf1): compute into B, PV(A), stage k+1 -> buf0
        PREFETCH(k + 1);
        QK_EXP_LOAD(1, pB0, pB1, vB0, vB1, vB2, vB3, vB4, vB5, vB6, vB7);
        PV_OTHER(pA0, pA1, vA0, vA1, vA2, vA3, vA4, vA5, vA6, vA7);
        STAGE_WRITE(0);
        __syncthreads();
        // tile k+1 (even -> buf0): compute into A, PV(B), stage k+2 -> buf1
        PREFETCH(k + 2);
        QK_EXP_LOAD(0, pA0, pA1, vA0, vA1, vA2, vA3, vA4, vA5, vA6, vA7);
        PV_OTHER(pB0, pB1, vB0, vB1, vB2, vB3, vB4, vB5, vB6, vB7);
        STAGE_WRITE(1);
        __syncthreads();
    }
    // tile 63 (buf1): compute into B, PV(A); no more staging
    QK_EXP_LOAD(1, pB0, pB1, vB0, vB1, vB2, vB3, vB4, vB5, vB6, vB7);
    PV_OTHER(pA0, pA1, vA0, vA1, vA2, vA3, vA4, vA5, vA6, vA7);
    // drain PV(B)
    PV_OTHER(pB0, pB1, vB0, vB1, vB2, vB3, vB4, vB5, vB6, vB7);

#undef QK_EXP_LOAD
#undef PV_OTHER
#undef PREFETCH
#undef STAGE_WRITE

    // ---- cross-kh combine + epilogue ----
    const float gam = gammap[0];
    float dall = dsum + __shfl_xor(dsum, 32);
    float* scr = (float*)&vlds[0][0];   // 32 KB scratch
    __syncthreads();   // all PV reads of vlds done; safe to reuse
    if (kh == 1) {
        #pragma unroll
        for (int ch = 0; ch < 4; ++ch)
            #pragma unroll
            for (int r = 0; r < 16; ++r)
                scr[(((cp * 4 + ch) * 16 + r) << 6) + l] = acc[ch][r];
    }
    if (cp == 0 && l < 32) dlds[kh][l31] = dall;
    __syncthreads();
    if (kh == 0) {
        const float denom = dlds[0][l31] + dlds[1][l31];
        const float ginv = gam / denom;
        const float* xb2 = x + (((size_t)b) << 8) * 4096;
        float* ob = out + (((size_t)b) << 8) * 4096;
        const int q = qbase + l31;
        #pragma unroll
        for (int ch = 0; ch < 4; ++ch) {
            #pragma unroll
            for (int r = 0; r < 16; ++r) {
                int c = cp * 128 + ch * 32 + ROWPAT(r, hi);
                float o = acc[ch][r] + scr[(((cp * 4 + ch) * 16 + r) << 6) + l];
                size_t idx = (size_t)c * 4096 + q;
                ob[idx] = o * ginv + xb2[idx];
            }
        }
    }
}

extern "C" void kernel_launch(void* const* d_in, const int* in_sizes, int n_in,
                              void* d_out, int out_size, void* d_ws, size_t ws_size,
                              hipStream_t stream) {
    (void)in_sizes; (void)n_in; (void)out_size; (void)ws_size;
    const float* x     = (const float*)d_in[0];
    const float* Wq    = (const float*)d_in[1];
    const float* bq    = (const float*)d_in[2];
    const float* Wk    = (const float*)d_in[3];
    const float* bk    = (const float*)d_in[4];
    const float* Wv    = (const float*)d_in[5];
    const float* bv    = (const float*)d_in[6];
    const float* gamma = (const float*)d_in[7];
    float* out = (float*)d_out;

    char* ws = (char*)d_ws;
    ushort* Wcb  = (ushort*)(ws + WCATB_OFF);
    ushort* qbuf = (ushort*)(ws + QBUF_OFF);
    ushort* kbuf = (ushort*)(ws + KBUF_OFF);
    ushort* vbuf = (ushort*)(ws + VBUF_OFF);

    prep_kernel<<<320, 256, 0, stream>>>(Wq, Wk, Wv, Wcb);
    fproj_kernel<<<512, 512, 0, stream>>>(x, Wcb, bq, bk, bv, qbuf, kbuf, vbuf);
    attn_kernel<<<512, 256, 0, stream>>>(qbuf, kbuf, vbuf, x, gamma, out);
}